// Round 1
// baseline (839.413 us; speedup 1.0000x reference)
//
#include <hip/hip_runtime.h>
#include <stdint.h>

#define B_ 8
#define T_ 2048
#define S_ 7
#define H_ 512
#define K_ 1024            // 2H
#define M_ (B_*T_*S_)      // 114688
#define BT_ (B_*T_)        // 16384

typedef __bf16 bf16;
typedef __attribute__((ext_vector_type(8))) __bf16 bf16x8;
typedef __attribute__((ext_vector_type(4))) float f32x4;

// ---------------------------------------------------------------------------
// Prep 1: Wm [1024][512] f32 (row-major [d][h]) -> WmT [512][1024] bf16 ([h][d])
// so GEMM B-operand fragments are contiguous along K.
__global__ __launch_bounds__(256) void wtrans_kernel(const float* __restrict__ Wm,
                                                     bf16* __restrict__ WmT) {
  __shared__ float tile[64][65];
  int bd = blockIdx.x >> 3;   // 16 d-tiles of 64
  int bh = blockIdx.x & 7;    // 8 h-tiles of 64
  int d0 = bd * 64, h0 = bh * 64;
  int t = threadIdx.x;
#pragma unroll
  for (int i = 0; i < 4; ++i) {
    int lin = i * 256 + t;          // 0..1023
    int dd = lin >> 4;              // 0..63
    int hh = (lin & 15) * 4;        // 0..60
    float4 v = *(const float4*)(Wm + (size_t)(d0 + dd) * H_ + h0 + hh);
    tile[dd][hh + 0] = v.x; tile[dd][hh + 1] = v.y;
    tile[dd][hh + 2] = v.z; tile[dd][hh + 3] = v.w;
  }
  __syncthreads();
#pragma unroll
  for (int i = 0; i < 2; ++i) {
    int lin = i * 256 + t;          // 0..511
    int hh = lin >> 3;              // 0..63
    int dc = lin & 7;               // chunk of 8 d
    bf16x8 o;
#pragma unroll
    for (int j = 0; j < 8; ++j) o[j] = (__bf16)tile[dc * 8 + j][hh];
    *(bf16x8*)(WmT + (size_t)(h0 + hh) * K_ + d0 + dc * 8) = o;
  }
}

// ---------------------------------------------------------------------------
// Prep 2: per-b suffix-min of update indices (backfill index).
// upd[t] = u>0 ? t : T ; nxt = suffix-min ; idx = nxt<T ? nxt : t
__global__ __launch_bounds__(1024) void idx_kernel(const int* __restrict__ u,
                                                   int* __restrict__ idxb) {
  __shared__ int s[T_];
  int b = blockIdx.x, t = threadIdx.x;
  int i0 = t, i1 = t + 1024;
  s[i0] = (u[b * T_ + i0] > 0) ? i0 : T_;
  s[i1] = (u[b * T_ + i1] > 0) ? i1 : T_;
  __syncthreads();
  for (int off = 1; off < T_; off <<= 1) {
    int a0 = s[i0], a1 = s[i1];
    int b0 = (i0 + off < T_) ? s[i0 + off] : 0x7FFFFFFF;
    int b1 = (i1 + off < T_) ? s[i1 + off] : 0x7FFFFFFF;
    __syncthreads();
    s[i0] = min(a0, b0);
    s[i1] = min(a1, b1);
    __syncthreads();
  }
  int n0 = s[i0]; idxb[b * T_ + i0] = (n0 < T_) ? n0 : i0;
  int n1 = s[i1]; idxb[b * T_ + i1] = (n1 < T_) ? n1 : i1;
}

// ---------------------------------------------------------------------------
// GEMM: msg[r][h] = relu(senders[r][:] . Wm[:][h] + bm[h]) * mask[r], bf16 out.
// 128x128 tile, BK=32, 4 waves (2x2), wave-tile 64x64 via mfma_f32_16x16x32_bf16.
#define BM 128
#define BN 128
#define BK 32
#define KSTEPS (K_/BK)       // 32
#define NTILES (H_/BN)       // 4
#define MTILES (M_/BM)       // 896
#define NWG (MTILES*NTILES)  // 3584

__device__ inline bf16x8 pack8(float4 x, float4 y) {
  bf16x8 r;
  r[0] = (__bf16)x.x; r[1] = (__bf16)x.y; r[2] = (__bf16)x.z; r[3] = (__bf16)x.w;
  r[4] = (__bf16)y.x; r[5] = (__bf16)y.y; r[6] = (__bf16)y.z; r[7] = (__bf16)y.w;
  return r;
}

__global__ __launch_bounds__(256, 2) void gemm_kernel(
    const float* __restrict__ A,    // senders [M][K]
    const bf16*  __restrict__ WmT,  // [N=512][K=1024] bf16
    const float* __restrict__ bm,   // [512]
    const float* __restrict__ mask, // [M]
    bf16* __restrict__ Cmsg)        // [M][512] bf16
{
  // LDS chunk layout: chunk (q, row) at [q*128 + row], chunk = 8 bf16 along K.
  __shared__ bf16x8 ldsA[4 * 128];
  __shared__ bf16x8 ldsW[4 * 128];

  // XCD-aware swizzle: 4 N-tiles of one M-tile run consecutively on one XCD.
  int bid = blockIdx.x;
  int sw = (bid & 7) * (NWG / 8) + (bid >> 3);
  int mTile = sw >> 2;
  int nTile = sw & 3;
  int m0 = mTile * BM;
  int n0 = nTile * BN;

  int tid = threadIdx.x;
  int lane = tid & 63;
  int wid = tid >> 6;
  int wm = wid >> 1, wn = wid & 1;
  int l15 = lane & 15, lq = lane >> 4;

  // staging: thread -> (row, half): loads 16 elements (k-local 16*half..+15)
  int srow = tid >> 1;      // 0..127
  int shalf = tid & 1;      // 0,1
  const float* aptr = A + (size_t)(m0 + srow) * K_ + 16 * shalf;
  const bf16*  wptr = WmT + (size_t)(n0 + srow) * K_ + 16 * shalf;
  int ci = (2 * shalf) * 128 + srow;  // LDS chunk index for q=2*shalf

  f32x4 acc[4][4];
#pragma unroll
  for (int i = 0; i < 4; ++i)
#pragma unroll
    for (int j = 0; j < 4; ++j) acc[i][j] = f32x4{0.f, 0.f, 0.f, 0.f};

  // prefetch k-step 0
  float4 pa0 = *(const float4*)(aptr + 0);
  float4 pa1 = *(const float4*)(aptr + 4);
  float4 pa2 = *(const float4*)(aptr + 8);
  float4 pa3 = *(const float4*)(aptr + 12);
  bf16x8 pw0 = *(const bf16x8*)(wptr);
  bf16x8 pw1 = *(const bf16x8*)(wptr + 8);

  for (int kt = 0; kt < KSTEPS; ++kt) {
    // write staged registers to LDS
    ldsA[ci]       = pack8(pa0, pa1);
    ldsA[ci + 128] = pack8(pa2, pa3);
    ldsW[ci]       = pw0;
    ldsW[ci + 128] = pw1;
    // prefetch next k-step (overlaps barrier + MFMA)
    if (kt + 1 < KSTEPS) {
      aptr += BK; wptr += BK;
      pa0 = *(const float4*)(aptr + 0);
      pa1 = *(const float4*)(aptr + 4);
      pa2 = *(const float4*)(aptr + 8);
      pa3 = *(const float4*)(aptr + 12);
      pw0 = *(const bf16x8*)(wptr);
      pw1 = *(const bf16x8*)(wptr + 8);
    }
    __syncthreads();
    bf16x8 af[4], bfg[4];
#pragma unroll
    for (int mi = 0; mi < 4; ++mi) af[mi] = ldsA[lq * 128 + 64 * wm + 16 * mi + l15];
#pragma unroll
    for (int ni = 0; ni < 4; ++ni) bfg[ni] = ldsW[lq * 128 + 64 * wn + 16 * ni + l15];
#pragma unroll
    for (int mi = 0; mi < 4; ++mi)
#pragma unroll
      for (int ni = 0; ni < 4; ++ni)
        acc[mi][ni] = __builtin_amdgcn_mfma_f32_16x16x32_bf16(af[mi], bfg[ni], acc[mi][ni], 0, 0, 0);
    __syncthreads();
  }

  // epilogue: relu(acc + bm) * mask -> bf16
  float bmv[4];
#pragma unroll
  for (int ni = 0; ni < 4; ++ni) bmv[ni] = bm[n0 + 64 * wn + 16 * ni + l15];
#pragma unroll
  for (int mi = 0; mi < 4; ++mi) {
    int rbase = m0 + 64 * wm + 16 * mi + 4 * lq;
#pragma unroll
    for (int j = 0; j < 4; ++j) {
      float mk = mask[rbase + j];
      size_t rowoff = (size_t)(rbase + j) * H_;
#pragma unroll
      for (int ni = 0; ni < 4; ++ni) {
        float v = acc[mi][ni][j] + bmv[ni];
        v = fmaxf(v, 0.f) * mk;
        Cmsg[rowoff + n0 + 64 * wn + 16 * ni + l15] = (__bf16)v;
      }
    }
  }
}

// ---------------------------------------------------------------------------
// Attention + softmax + agg + hx gather. One wave per (b,t).
__global__ __launch_bounds__(256) void attn_kernel(
    const float* __restrict__ query, const bf16* __restrict__ msg,
    const float* __restrict__ mask, const float* __restrict__ hx,
    const int* __restrict__ idxb, float* __restrict__ out)
{
  int g = blockIdx.x * 4 + (threadIdx.x >> 6);  // flat (b,t)
  int lane = threadIdx.x & 63;
  int h0 = lane * 8;

  const float* qp = query + (size_t)g * H_ + h0;
  float4 q0 = *(const float4*)qp, q1 = *(const float4*)(qp + 4);
  float qv[8] = {q0.x, q0.y, q0.z, q0.w, q1.x, q1.y, q1.z, q1.w};

  float mf[7][8];
  float dots[7];
#pragma unroll
  for (int s = 0; s < 7; ++s) {
    uint4 raw = *(const uint4*)(msg + ((size_t)g * 7 + s) * H_ + h0);
    unsigned int w[4] = {raw.x, raw.y, raw.z, raw.w};
    float d = 0.f;
#pragma unroll
    for (int p = 0; p < 4; ++p) {
      float lo = __uint_as_float(w[p] << 16);
      float hi = __uint_as_float(w[p] & 0xffff0000u);
      mf[s][2 * p] = lo; mf[s][2 * p + 1] = hi;
      d += qv[2 * p] * lo + qv[2 * p + 1] * hi;
    }
    dots[s] = d;
  }
#pragma unroll
  for (int s = 0; s < 7; ++s) {
    float d = dots[s];
#pragma unroll
    for (int o = 32; o > 0; o >>= 1) d += __shfl_xor(d, o);
    dots[s] = d;
  }

  const float scale = 0.044194173824159216f;  // 1/sqrt(512)
  float mk[7];
#pragma unroll
  for (int s = 0; s < 7; ++s) mk[s] = mask[(size_t)g * 7 + s];
  float mmax = -INFINITY;
#pragma unroll
  for (int s = 0; s < 7; ++s)
    if (mk[s] > 0.f) mmax = fmaxf(mmax, dots[s] * scale);
  float p[7], denom = 0.f;
#pragma unroll
  for (int s = 0; s < 7; ++s) {
    p[s] = (mk[s] > 0.f) ? __expf(dots[s] * scale - mmax) : 0.f;
    denom += p[s];
  }
  float inv = (denom > 0.f) ? 1.f / denom : 0.f;  // fully-masked row -> 0

  float o[8] = {0.f, 0.f, 0.f, 0.f, 0.f, 0.f, 0.f, 0.f};
#pragma unroll
  for (int s = 0; s < 7; ++s)
#pragma unroll
    for (int j = 0; j < 8; ++j) o[j] += p[s] * mf[s][j];

  float* op = out + (size_t)g * 1024 + h0;
  float4 o0 = {o[0] * inv, o[1] * inv, o[2] * inv, o[3] * inv};
  float4 o1 = {o[4] * inv, o[5] * inv, o[6] * inv, o[7] * inv};
  *(float4*)(op) = o0;
  *(float4*)(op + 4) = o1;

  // hidden backfill gather
  int b = g >> 11;
  int idx = idxb[g];
  const float* hp = hx + ((size_t)(b << 11) + idx) * H_ + h0;
  float4 h1 = *(const float4*)hp;
  float4 h2 = *(const float4*)(hp + 4);
  *(float4*)(op + 512) = h1;
  *(float4*)(op + 516) = h2;
}

// ---------------------------------------------------------------------------
extern "C" void kernel_launch(void* const* d_in, const int* in_sizes, int n_in,
                              void* d_out, int out_size, void* d_ws, size_t ws_size,
                              hipStream_t stream) {
  const float* query   = (const float*)d_in[0];
  const float* senders = (const float*)d_in[1];
  const float* smask   = (const float*)d_in[2];
  const float* Wm      = (const float*)d_in[3];
  const float* bm      = (const float*)d_in[4];
  const float* hx      = (const float*)d_in[5];
  const int*   u       = (const int*)d_in[6];
  float* out = (float*)d_out;

  char* ws = (char*)d_ws;
  bf16* msg  = (bf16*)ws;                                   // 114688*512*2 = 117440512 B
  bf16* WmT  = (bf16*)(ws + 117440512);                     // 1 MiB
  int*  idxb = (int*)(ws + 117440512 + 1048576);            // 64 KiB

  wtrans_kernel<<<128, 256, 0, stream>>>(Wm, WmT);
  idx_kernel<<<B_, 1024, 0, stream>>>(u, idxb);
  gemm_kernel<<<NWG, 256, 0, stream>>>(senders, WmT, bm, smask, msg);
  attn_kernel<<<BT_ / 4, 256, 0, stream>>>(query, msg, smask, hx, idxb, out);
}